// Round 7
// baseline (473.444 us; speedup 1.0000x reference)
//
#include <hip/hip_runtime.h>

#define N_NODES 8192
#define CAP 128    // neighbor capacity; Binomial(8192,1/256): P(deg>128) ~ 0
#define ETILE 16   // nodes per MLP tile
#define NSEG (N_NODES * N_NODES / 256)  // 1KB wave-segments (256 floats each)
constexpr int AST = 132;  // activation LDS row stride (floats), 16B-aligned
constexpr int WST = 129;  // weight LDS row stride (k-major), +1 pad

// ---------------------------------------------------------------------------
// Kernel 0: zero the degree counters (ws is poisoned 0xAA).
// ---------------------------------------------------------------------------
__global__ void zero_cnt_kernel(int* __restrict__ cnt) {
  cnt[blockIdx.x * 256 + threadIdx.x] = 0;
}

// ---------------------------------------------------------------------------
// Kernel 1: adj scan -> CSR, LINEAR GLOBAL STREAM.
// Grid-stride over flat adj in 1KB wave-segments: at any instant all 8192
// resident waves touch one sliding ~8MB window (copy-like DRAM locality),
// instead of 4096 private 32KB row streams. CSR slot order is irrelevant for
// the aggregation, so slots are reserved with one global atomicAdd per
// non-empty wave-segment (~165k atomics / 8192 rows: negligible contention).
// ---------------------------------------------------------------------------
__global__ __launch_bounds__(256, 8) void scan_kernel(
    const float* __restrict__ adj, int* __restrict__ cnt,
    int* __restrict__ nbr) {
  const int t = threadIdx.x;
  const int lane = t & 63;
  const int nw = gridDim.x * 4;                 // total waves
  const int gw = blockIdx.x * 4 + (t >> 6);     // this wave
  const unsigned long long lmask = (1ull << lane) - 1;
  const uint4* adj4 = (const uint4*)adj;

  int s = gw;
  uint4 v = adj4[(size_t)s * 64 + lane];
  while (s < NSEG) {
    const int sn = s + nw;
    uint4 vn;
    if (sn < NSEG) vn = adj4[(size_t)sn * 64 + lane];  // prefetch next segment
    // ---- process current segment ----
    const unsigned long long m0 = __ballot(v.x != 0u);
    const unsigned long long m1 = __ballot(v.y != 0u);
    const unsigned long long m2 = __ballot(v.z != 0u);
    const unsigned long long m3 = __ballot(v.w != 0u);
    const int total = (int)(__popcll(m0) + __popcll(m1) + __popcll(m2) + __popcll(m3));
    if (total) {
      const int row = s >> 5;                       // 32 segments per row
      const int colbase = (s & 31) * 256 + lane * 4;
      int base;
      if (lane == 0) base = atomicAdd(&cnt[row], total);
      base = __shfl(base, 0);
      int* nr = nbr + (size_t)row * CAP;
      if (v.x != 0u) { int p = base + (int)__popcll(m0 & lmask); if (p < CAP) nr[p] = colbase + 0; }
      base += (int)__popcll(m0);
      if (v.y != 0u) { int p = base + (int)__popcll(m1 & lmask); if (p < CAP) nr[p] = colbase + 1; }
      base += (int)__popcll(m1);
      if (v.z != 0u) { int p = base + (int)__popcll(m2 & lmask); if (p < CAP) nr[p] = colbase + 2; }
      base += (int)__popcll(m2);
      if (v.w != 0u) { int p = base + (int)__popcll(m3 & lmask); if (p < CAP) nr[p] = colbase + 3; }
    }
    v = vn;
    s = sn;
  }
}

// ---------------------------------------------------------------------------
// LDS-resident MLP layer for a tile of TILE nodes, 256 threads.
// SCALEMODE: 0 = none, 1 = multiply by rowscale[node] (mask),
//            2 = multiply by rsqrt(cnt[node]+1) (dinv).
// ---------------------------------------------------------------------------
template <int TILE, int K, int KSPLIT, int F, bool RELU, bool BIAS, int SCALEMODE>
__device__ __forceinline__ void layer_op(
    const float (*__restrict__ A0)[AST], const float (*__restrict__ A1)[AST],
    float (*__restrict__ Aout)[AST], float (*__restrict__ Wb)[WST],
    const float* __restrict__ W, const float* __restrict__ bias,
    float* __restrict__ gout, const float* __restrict__ rowscale,
    const int* __restrict__ degcnt, int n0, int t) {
  constexpr int KC = 32;
  constexpr int NCH = K / KC;
  constexpr int ACT = (F * TILE < 256) ? F * TILE : 256;
  constexpr int RS = ACT / F;
  constexpr int RPT = TILE / RS;
  const int c = t % F;
  const int rb = t / F;
  float acc[RPT];
#pragma unroll
  for (int i = 0; i < RPT; ++i) acc[i] = 0.f;

  for (int ch = 0; ch < NCH; ++ch) {
#pragma unroll
    for (int i = 0; i < (F * KC + 255) / 256; ++i) {  // stage W chunk, k-major
      int lin = t + i * 256;
      if ((F * KC) % 256 == 0 || lin < F * KC) {
        int k = lin % KC, f = lin / KC;
        Wb[k][f] = W[(size_t)f * K + ch * KC + k];
      }
    }
    __syncthreads();
    if (t < ACT) {
      const float (*__restrict__ As)[AST] = (ch * KC < KSPLIT) ? A0 : A1;
      const int kb = (ch * KC < KSPLIT) ? ch * KC : ch * KC - KSPLIT;
#pragma unroll
      for (int kg = 0; kg < KC / 4; ++kg) {
        float w0 = Wb[kg * 4 + 0][c];
        float w1v = Wb[kg * 4 + 1][c];
        float w2v = Wb[kg * 4 + 2][c];
        float w3v = Wb[kg * 4 + 3][c];
#pragma unroll
        for (int i = 0; i < RPT; ++i) {
          const float4 a = *(const float4*)&As[rb + i * RS][kb + kg * 4];
          acc[i] = fmaf(a.x, w0, acc[i]);
          acc[i] = fmaf(a.y, w1v, acc[i]);
          acc[i] = fmaf(a.z, w2v, acc[i]);
          acc[i] = fmaf(a.w, w3v, acc[i]);
        }
      }
    }
    __syncthreads();
  }
  if (t < ACT) {
#pragma unroll
    for (int i = 0; i < RPT; ++i) {
      float v = acc[i];
      if (BIAS) v += bias[c];
      if (RELU) v = fmaxf(v, 0.f);
      int node = n0 + rb + i * RS;
      if (SCALEMODE == 1) v *= rowscale[node];
      if (SCALEMODE == 2) v *= rsqrtf((float)degcnt[node] + 1.0f);
      if (Aout) Aout[rb + i * RS][c] = v;
      if (gout) gout[(size_t)node * F + c] = v;
    }
  }
}

// ---------------------------------------------------------------------------
// Kernel 2: encoder x -> h1 -> h ; msg = (h @ wg.T) * dinv  (512 blocks)
// ---------------------------------------------------------------------------
__global__ __launch_bounds__(256) void encode_kernel(
    const float* __restrict__ x,
    const float* __restrict__ w1, const float* __restrict__ b1,
    const float* __restrict__ w2, const float* __restrict__ b2,
    const float* __restrict__ wg, const int* __restrict__ cnt,
    float* __restrict__ h_out, float* __restrict__ msg_out) {
  __shared__ float bufA[ETILE][AST];
  __shared__ float bufB[ETILE][AST];
  __shared__ float Wb[32][WST];
  const int t = threadIdx.x;
  const int n0 = blockIdx.x * ETILE;
  if (t < 128) {  // stage x tile: 16x32 floats = 128 float4
    int row = t >> 3, k4 = (t & 7) * 4;
    *(float4*)&bufA[row][k4] = *(const float4*)&x[(size_t)(n0 + row) * 32 + k4];
  }
  layer_op<ETILE, 32, 32, 64, true, true, 0>(bufA, nullptr, bufB, Wb, w1, b1, nullptr, nullptr, nullptr, n0, t);
  layer_op<ETILE, 64, 64, 128, true, true, 0>(bufB, nullptr, bufA, Wb, w2, b2, h_out, nullptr, nullptr, n0, t);
  layer_op<ETILE, 128, 128, 128, false, false, 2>(bufA, nullptr, nullptr, Wb, wg, nullptr, msg_out, nullptr, cnt, n0, t);
}

// ---------------------------------------------------------------------------
// Kernel 3: agg. 2 rows per 256-thread block, barrier-free gathers.
// g1 = relu(dinv_i * (msg'_i + sum_j msg'_j) + bg), msg' pre-scaled by dinv.
// ---------------------------------------------------------------------------
__global__ __launch_bounds__(256) void agg_kernel(
    const int* __restrict__ cnt, const int* __restrict__ nbr,
    const float* __restrict__ msg, const float* __restrict__ bg,
    const float* __restrict__ adj, float* __restrict__ g1) {
  const int t = threadIdx.x;
  const int f = t & 127;
  const int row = blockIdx.x * 2 + (t >> 7);
  float acc = msg[(size_t)row * 128 + f];  // self-loop term
  const int c = cnt[row];
  const float dv = rsqrtf((float)c + 1.0f);
  if (c <= CAP) {
    int i = 0;
    for (; i + 4 <= c; i += 4) {
      int j0 = nbr[(size_t)row * CAP + i + 0];
      int j1 = nbr[(size_t)row * CAP + i + 1];
      int j2 = nbr[(size_t)row * CAP + i + 2];
      int j3 = nbr[(size_t)row * CAP + i + 3];
      float a0 = msg[(size_t)j0 * 128 + f];
      float a1 = msg[(size_t)j1 * 128 + f];
      float a2 = msg[(size_t)j2 * 128 + f];
      float a3 = msg[(size_t)j3 * 128 + f];
      acc += (a0 + a1) + (a2 + a3);
    }
    for (; i < c; ++i) {
      int j = nbr[(size_t)row * CAP + i];
      acc += msg[(size_t)j * 128 + f];
    }
  } else {  // statistically unreachable dense fallback (re-reads adj row)
    acc = msg[(size_t)row * 128 + f];
    for (int col = 0; col < N_NODES; ++col) {
      if (adj[(size_t)row * N_NODES + col] != 0.f) acc += msg[(size_t)col * 128 + f];
    }
  }
  float v = fmaf(dv, acc, bg[f]);
  g1[(size_t)row * 128 + f] = fmaxf(v, 0.f);
}

// ---------------------------------------------------------------------------
// Kernel 4: decoder g1 -> g2 -> p1([g2|h]) -> p2 -> out * mask  (512 blocks)
// ---------------------------------------------------------------------------
__global__ __launch_bounds__(256) void decode_kernel(
    const float* __restrict__ g1, const float* __restrict__ h,
    const float* __restrict__ wd, const float* __restrict__ bd,
    const float* __restrict__ wp1, const float* __restrict__ bp1,
    const float* __restrict__ wp2, const float* __restrict__ bp2,
    const float* __restrict__ wo, const float* __restrict__ bo,
    const float* __restrict__ mask, float* __restrict__ out) {
  __shared__ float bufA[ETILE][AST];
  __shared__ float bufB[ETILE][AST];
  __shared__ float bufH[ETILE][AST];
  __shared__ float Wb[32][WST];
  const int t = threadIdx.x;
  const int n0 = blockIdx.x * ETILE;
#pragma unroll
  for (int i = 0; i < 2; ++i) {  // stage g1 and h tiles (16x128 each)
    int lin = t + i * 256;
    int row = lin >> 5, k4 = (lin & 31) * 4;
    *(float4*)&bufA[row][k4] = *(const float4*)&g1[(size_t)(n0 + row) * 128 + k4];
    *(float4*)&bufH[row][k4] = *(const float4*)&h[(size_t)(n0 + row) * 128 + k4];
  }
  layer_op<ETILE, 128, 128, 128, true, true, 0>(bufA, nullptr, bufB, Wb, wd, bd, nullptr, nullptr, nullptr, n0, t);
  layer_op<ETILE, 256, 128, 128, true, true, 0>(bufB, bufH, bufA, Wb, wp1, bp1, nullptr, nullptr, nullptr, n0, t);
  layer_op<ETILE, 128, 128, 64, true, true, 0>(bufA, nullptr, bufB, Wb, wp2, bp2, nullptr, nullptr, nullptr, n0, t);
  layer_op<ETILE, 64, 64, 8, false, true, 1>(bufB, nullptr, nullptr, Wb, wo, bo, out, mask, nullptr, n0, t);
}

extern "C" void kernel_launch(void* const* d_in, const int* in_sizes, int n_in,
                              void* d_out, int out_size, void* d_ws, size_t ws_size,
                              hipStream_t stream) {
  const float* x    = (const float*)d_in[0];
  const float* adj  = (const float*)d_in[1];
  const float* mask = (const float*)d_in[2];
  const float* w1   = (const float*)d_in[3];
  const float* b1   = (const float*)d_in[4];
  const float* w2   = (const float*)d_in[5];
  const float* b2   = (const float*)d_in[6];
  const float* wg   = (const float*)d_in[7];
  const float* bg   = (const float*)d_in[8];
  const float* wd   = (const float*)d_in[9];
  const float* bd   = (const float*)d_in[10];
  const float* wp1  = (const float*)d_in[11];
  const float* bp1  = (const float*)d_in[12];
  const float* wp2  = (const float*)d_in[13];
  const float* bp2  = (const float*)d_in[14];
  const float* wo   = (const float*)d_in[15];
  const float* bo   = (const float*)d_in[16];
  float* out = (float*)d_out;

  float* ws = (float*)d_ws;
  float* h    = ws; ws += (size_t)N_NODES * 128;
  float* msg  = ws; ws += (size_t)N_NODES * 128;
  float* g1   = ws; ws += (size_t)N_NODES * 128;
  int* cnt = (int*)ws; ws += N_NODES;
  int* nbr = (int*)ws;  // N_NODES * CAP ints

  zero_cnt_kernel<<<N_NODES / 256, 256, 0, stream>>>(cnt);
  scan_kernel<<<2048, 256, 0, stream>>>(adj, cnt, nbr);
  encode_kernel<<<N_NODES / ETILE, 256, 0, stream>>>(x, w1, b1, w2, b2, wg, cnt, h, msg);
  agg_kernel<<<N_NODES / 2, 256, 0, stream>>>(cnt, nbr, msg, bg, adj, g1);
  decode_kernel<<<N_NODES / ETILE, 256, 0, stream>>>(
      g1, h, wd, bd, wp1, bp1, wp2, bp2, wo, bo, mask, out);
}

// Round 8
// 465.214 us; speedup vs baseline: 1.0177x; 1.0177x over previous
//
#include <hip/hip_runtime.h>

#define N_NODES 8192
#define CAP 128    // neighbor capacity; Binomial(8192,1/256): P(deg>128) ~ 0
#define ETILE 16   // nodes per MLP tile
constexpr int AST = 132;  // activation LDS row stride (floats), 16B-aligned
constexpr int WST = 129;  // weight LDS row stride (k-major), +1 pad

// async global->LDS DMA, 16B per lane, wave-uniform LDS base (+lane*16 implicit)
#define GLDS16(gsrc, ldst)                                                      \
  __builtin_amdgcn_global_load_lds(                                             \
      (const __attribute__((address_space(1))) void*)(gsrc),                    \
      (__attribute__((address_space(3))) void*)(ldst), 16, 0, 0)

// ---------------------------------------------------------------------------
// Kernel 1: adj scan -> CSR via the ASYNC DMA PATH (global_load_lds).
// One row per wave; row = 4 chunks of 8KB staged by 8 width-16 DMA insts,
// double-buffered with fine-grained vmcnt(8) (prefetch never drained).
// Ballot/emit identical to the proven R6 scheme; no atomics, exact cnt.
// ---------------------------------------------------------------------------
__global__ __launch_bounds__(256, 2) void scan_kernel(
    const float* __restrict__ adj, int* __restrict__ cnt,
    int* __restrict__ nbr) {
  __shared__ uint4 stage[4][2][512];  // per wave: 2 x 8KB
  const int t = threadIdx.x;
  const int lane = t & 63;
  const int w = t >> 6;
  const int row = blockIdx.x * 4 + w;
  const float* rowg = adj + (size_t)row * N_NODES;
  const unsigned long long lmask = (1ull << lane) - 1;

  // prologue: chunk 0 -> buffer 0
#pragma unroll
  for (int i = 0; i < 8; ++i)
    GLDS16(rowg + i * 256 + lane * 4, &stage[w][0][i * 64]);

  int running = 0;
  int* nbr_row = nbr + (size_t)row * CAP;
#pragma unroll
  for (int ch = 0; ch < 4; ++ch) {
    if (ch < 3) {  // prefetch chunk ch+1 into the other buffer
#pragma unroll
      for (int i = 0; i < 8; ++i)
        GLDS16(rowg + (ch + 1) * 2048 + i * 256 + lane * 4,
               &stage[w][(ch + 1) & 1][i * 64]);
      __builtin_amdgcn_s_waitcnt(0x3F78);  // vmcnt(8): chunk ch landed, prefetch in flight
    } else {
      __builtin_amdgcn_s_waitcnt(0x3F70);  // vmcnt(0): last chunk
    }
    asm volatile("" ::: "memory");  // compiler fence: no ds_read hoisting
    uint4 v[8];
#pragma unroll
    for (int i = 0; i < 8; ++i) v[i] = stage[w][ch & 1][i * 64 + lane];
    // branchless per-lane nonzero count
    int c = 0;
#pragma unroll
    for (int i = 0; i < 8; ++i)
      c += (v[i].x != 0u) + (v[i].y != 0u) + (v[i].z != 0u) + (v[i].w != 0u);
    // wave-inclusive prefix scan (shuffles only; no barrier)
    int incl = c;
#pragma unroll
    for (int s = 1; s < 64; s <<= 1) {
      int n = __shfl_up(incl, s);
      if (lane >= s) incl += n;
    }
    int off = running + incl - c;  // exclusive per-lane start
    running += __shfl(incl, 63);
    const int colbase = ch * 2048;
#pragma unroll
    for (int i = 0; i < 8; ++i) {
      if (v[i].x | v[i].y | v[i].z | v[i].w) {
        const int col = colbase + (i * 64 + lane) * 4;
        if (v[i].x) { if (off < CAP) nbr_row[off] = col + 0; ++off; }
        if (v[i].y) { if (off < CAP) nbr_row[off] = col + 1; ++off; }
        if (v[i].z) { if (off < CAP) nbr_row[off] = col + 2; ++off; }
        if (v[i].w) { if (off < CAP) nbr_row[off] = col + 3; ++off; }
      }
    }
  }
  if (lane == 0) cnt[row] = running;
}

// ---------------------------------------------------------------------------
// LDS-resident MLP layer for a tile of TILE nodes, 256 threads.
// SCALEMODE: 0 = none, 1 = rowscale[node] (mask), 2 = rsqrt(cnt[node]+1).
// ---------------------------------------------------------------------------
template <int TILE, int K, int KSPLIT, int F, bool RELU, bool BIAS, int SCALEMODE>
__device__ __forceinline__ void layer_op(
    const float (*__restrict__ A0)[AST], const float (*__restrict__ A1)[AST],
    float (*__restrict__ Aout)[AST], float (*__restrict__ Wb)[WST],
    const float* __restrict__ W, const float* __restrict__ bias,
    float* __restrict__ gout, const float* __restrict__ rowscale,
    const int* __restrict__ degcnt, int n0, int t) {
  constexpr int KC = 32;
  constexpr int NCH = K / KC;
  constexpr int ACT = (F * TILE < 256) ? F * TILE : 256;
  constexpr int RS = ACT / F;
  constexpr int RPT = TILE / RS;
  const int c = t % F;
  const int rb = t / F;
  float acc[RPT];
#pragma unroll
  for (int i = 0; i < RPT; ++i) acc[i] = 0.f;

  for (int ch = 0; ch < NCH; ++ch) {
#pragma unroll
    for (int i = 0; i < (F * KC + 255) / 256; ++i) {  // stage W chunk, k-major
      int lin = t + i * 256;
      if ((F * KC) % 256 == 0 || lin < F * KC) {
        int k = lin % KC, f = lin / KC;
        Wb[k][f] = W[(size_t)f * K + ch * KC + k];
      }
    }
    __syncthreads();
    if (t < ACT) {
      const float (*__restrict__ As)[AST] = (ch * KC < KSPLIT) ? A0 : A1;
      const int kb = (ch * KC < KSPLIT) ? ch * KC : ch * KC - KSPLIT;
#pragma unroll
      for (int kg = 0; kg < KC / 4; ++kg) {
        float w0 = Wb[kg * 4 + 0][c];
        float w1v = Wb[kg * 4 + 1][c];
        float w2v = Wb[kg * 4 + 2][c];
        float w3v = Wb[kg * 4 + 3][c];
#pragma unroll
        for (int i = 0; i < RPT; ++i) {
          const float4 a = *(const float4*)&As[rb + i * RS][kb + kg * 4];
          acc[i] = fmaf(a.x, w0, acc[i]);
          acc[i] = fmaf(a.y, w1v, acc[i]);
          acc[i] = fmaf(a.z, w2v, acc[i]);
          acc[i] = fmaf(a.w, w3v, acc[i]);
        }
      }
    }
    __syncthreads();
  }
  if (t < ACT) {
#pragma unroll
    for (int i = 0; i < RPT; ++i) {
      float v = acc[i];
      if (BIAS) v += bias[c];
      if (RELU) v = fmaxf(v, 0.f);
      int node = n0 + rb + i * RS;
      if (SCALEMODE == 1) v *= rowscale[node];
      if (SCALEMODE == 2) v *= rsqrtf((float)degcnt[node] + 1.0f);
      if (Aout) Aout[rb + i * RS][c] = v;
      if (gout) gout[(size_t)node * F + c] = v;
    }
  }
}

// ---------------------------------------------------------------------------
// Kernel 2: encoder x -> h1 -> h ; msg = (h @ wg.T) * dinv  (512 blocks)
// ---------------------------------------------------------------------------
__global__ __launch_bounds__(256) void encode_kernel(
    const float* __restrict__ x,
    const float* __restrict__ w1, const float* __restrict__ b1,
    const float* __restrict__ w2, const float* __restrict__ b2,
    const float* __restrict__ wg, const int* __restrict__ cnt,
    float* __restrict__ h_out, float* __restrict__ msg_out) {
  __shared__ float bufA[ETILE][AST];
  __shared__ float bufB[ETILE][AST];
  __shared__ float Wb[32][WST];
  const int t = threadIdx.x;
  const int n0 = blockIdx.x * ETILE;
  if (t < 128) {  // stage x tile: 16x32 floats = 128 float4
    int row = t >> 3, k4 = (t & 7) * 4;
    *(float4*)&bufA[row][k4] = *(const float4*)&x[(size_t)(n0 + row) * 32 + k4];
  }
  layer_op<ETILE, 32, 32, 64, true, true, 0>(bufA, nullptr, bufB, Wb, w1, b1, nullptr, nullptr, nullptr, n0, t);
  layer_op<ETILE, 64, 64, 128, true, true, 0>(bufB, nullptr, bufA, Wb, w2, b2, h_out, nullptr, nullptr, n0, t);
  layer_op<ETILE, 128, 128, 128, false, false, 2>(bufA, nullptr, nullptr, Wb, wg, nullptr, msg_out, nullptr, cnt, n0, t);
}

// ---------------------------------------------------------------------------
// Kernel 3: agg. 2 rows per 256-thread block, barrier-free gathers.
// ---------------------------------------------------------------------------
__global__ __launch_bounds__(256) void agg_kernel(
    const int* __restrict__ cnt, const int* __restrict__ nbr,
    const float* __restrict__ msg, const float* __restrict__ bg,
    const float* __restrict__ adj, float* __restrict__ g1) {
  const int t = threadIdx.x;
  const int f = t & 127;
  const int row = blockIdx.x * 2 + (t >> 7);
  float acc = msg[(size_t)row * 128 + f];  // self-loop term
  const int c = cnt[row];
  const float dv = rsqrtf((float)c + 1.0f);
  if (c <= CAP) {
    int i = 0;
    for (; i + 4 <= c; i += 4) {
      int j0 = nbr[(size_t)row * CAP + i + 0];
      int j1 = nbr[(size_t)row * CAP + i + 1];
      int j2 = nbr[(size_t)row * CAP + i + 2];
      int j3 = nbr[(size_t)row * CAP + i + 3];
      float a0 = msg[(size_t)j0 * 128 + f];
      float a1 = msg[(size_t)j1 * 128 + f];
      float a2 = msg[(size_t)j2 * 128 + f];
      float a3 = msg[(size_t)j3 * 128 + f];
      acc += (a0 + a1) + (a2 + a3);
    }
    for (; i < c; ++i) {
      int j = nbr[(size_t)row * CAP + i];
      acc += msg[(size_t)j * 128 + f];
    }
  } else {  // statistically unreachable dense fallback (re-reads adj row)
    acc = msg[(size_t)row * 128 + f];
    for (int col = 0; col < N_NODES; ++col) {
      if (adj[(size_t)row * N_NODES + col] != 0.f) acc += msg[(size_t)col * 128 + f];
    }
  }
  float v = fmaf(dv, acc, bg[f]);
  g1[(size_t)row * 128 + f] = fmaxf(v, 0.f);
}

// ---------------------------------------------------------------------------
// Kernel 4: decoder g1 -> g2 -> p1([g2|h]) -> p2 -> out * mask  (512 blocks)
// ---------------------------------------------------------------------------
__global__ __launch_bounds__(256) void decode_kernel(
    const float* __restrict__ g1, const float* __restrict__ h,
    const float* __restrict__ wd, const float* __restrict__ bd,
    const float* __restrict__ wp1, const float* __restrict__ bp1,
    const float* __restrict__ wp2, const float* __restrict__ bp2,
    const float* __restrict__ wo, const float* __restrict__ bo,
    const float* __restrict__ mask, float* __restrict__ out) {
  __shared__ float bufA[ETILE][AST];
  __shared__ float bufB[ETILE][AST];
  __shared__ float bufH[ETILE][AST];
  __shared__ float Wb[32][WST];
  const int t = threadIdx.x;
  const int n0 = blockIdx.x * ETILE;
#pragma unroll
  for (int i = 0; i < 2; ++i) {  // stage g1 and h tiles (16x128 each)
    int lin = t + i * 256;
    int row = lin >> 5, k4 = (lin & 31) * 4;
    *(float4*)&bufA[row][k4] = *(const float4*)&g1[(size_t)(n0 + row) * 128 + k4];
    *(float4*)&bufH[row][k4] = *(const float4*)&h[(size_t)(n0 + row) * 128 + k4];
  }
  layer_op<ETILE, 128, 128, 128, true, true, 0>(bufA, nullptr, bufB, Wb, wd, bd, nullptr, nullptr, nullptr, n0, t);
  layer_op<ETILE, 256, 128, 128, true, true, 0>(bufB, bufH, bufA, Wb, wp1, bp1, nullptr, nullptr, nullptr, n0, t);
  layer_op<ETILE, 128, 128, 64, true, true, 0>(bufA, nullptr, bufB, Wb, wp2, bp2, nullptr, nullptr, nullptr, n0, t);
  layer_op<ETILE, 64, 64, 8, false, true, 1>(bufB, nullptr, nullptr, Wb, wo, bo, out, mask, nullptr, n0, t);
}

extern "C" void kernel_launch(void* const* d_in, const int* in_sizes, int n_in,
                              void* d_out, int out_size, void* d_ws, size_t ws_size,
                              hipStream_t stream) {
  const float* x    = (const float*)d_in[0];
  const float* adj  = (const float*)d_in[1];
  const float* mask = (const float*)d_in[2];
  const float* w1   = (const float*)d_in[3];
  const float* b1   = (const float*)d_in[4];
  const float* w2   = (const float*)d_in[5];
  const float* b2   = (const float*)d_in[6];
  const float* wg   = (const float*)d_in[7];
  const float* bg   = (const float*)d_in[8];
  const float* wd   = (const float*)d_in[9];
  const float* bd   = (const float*)d_in[10];
  const float* wp1  = (const float*)d_in[11];
  const float* bp1  = (const float*)d_in[12];
  const float* wp2  = (const float*)d_in[13];
  const float* bp2  = (const float*)d_in[14];
  const float* wo   = (const float*)d_in[15];
  const float* bo   = (const float*)d_in[16];
  float* out = (float*)d_out;

  float* ws = (float*)d_ws;
  float* h    = ws; ws += (size_t)N_NODES * 128;
  float* msg  = ws; ws += (size_t)N_NODES * 128;
  float* g1   = ws; ws += (size_t)N_NODES * 128;
  int* cnt = (int*)ws; ws += N_NODES;
  int* nbr = (int*)ws;  // N_NODES * CAP ints

  scan_kernel<<<N_NODES / 4, 256, 0, stream>>>(adj, cnt, nbr);
  encode_kernel<<<N_NODES / ETILE, 256, 0, stream>>>(x, w1, b1, w2, b2, wg, cnt, h, msg);
  agg_kernel<<<N_NODES / 2, 256, 0, stream>>>(cnt, nbr, msg, bg, adj, g1);
  decode_kernel<<<N_NODES / ETILE, 256, 0, stream>>>(
      g1, h, wd, bd, wp1, bp1, wp2, bp2, wo, bo, mask, out);
}

// Round 9
// 455.297 us; speedup vs baseline: 1.0399x; 1.0218x over previous
//
#include <hip/hip_runtime.h>

#define N_NODES 8192
#define CAP 128    // neighbor capacity; Binomial(8192,1/256): P(deg>128) ~ 0
#define ETILE 16   // nodes per encoder tile
#define DTILE 8    // nodes per decoder tile (1024 blocks -> 4+ blocks/CU)
constexpr int AST = 132;  // activation LDS row stride (floats), 16B-aligned
constexpr int WST = 129;  // weight LDS row stride (k-major), +1 pad

typedef unsigned u32x4 __attribute__((ext_vector_type(4)));

// ---------------------------------------------------------------------------
// Kernel 1: adj scan -> CSR. One row per wave, zero barriers, chunk-level
// double buffer (proven R6 structure). Loads are NONTEMPORAL (streaming,
// no L2/L3 allocate) -- adj has zero reuse; tests allocate-on-miss wall.
// ---------------------------------------------------------------------------
__global__ __launch_bounds__(256, 4) void scan_kernel(
    const float* __restrict__ adj, int* __restrict__ cnt,
    int* __restrict__ nbr) {
  const int t = threadIdx.x;
  const int lane = t & 63;
  const int row = blockIdx.x * 4 + (t >> 6);
  const u32x4* rowp = (const u32x4*)(adj + (size_t)row * N_NODES);
  u32x4 v[8], vn[8];
#pragma unroll
  for (int i = 0; i < 8; ++i) v[i] = __builtin_nontemporal_load(&rowp[i * 64 + lane]);
  int running = 0;
  int* nbr_row = nbr + (size_t)row * CAP;
  for (int ch = 0; ch < 4; ++ch) {
    if (ch < 3) {  // prefetch next chunk while consuming current
      const u32x4* cp = rowp + (ch + 1) * 512;
#pragma unroll
      for (int i = 0; i < 8; ++i) vn[i] = __builtin_nontemporal_load(&cp[i * 64 + lane]);
    }
    int c = 0;
#pragma unroll
    for (int i = 0; i < 8; ++i)
      c += (v[i].x != 0u) + (v[i].y != 0u) + (v[i].z != 0u) + (v[i].w != 0u);
    int incl = c;  // wave-inclusive prefix scan, shuffles only
#pragma unroll
    for (int s = 1; s < 64; s <<= 1) {
      int n = __shfl_up(incl, s);
      if (lane >= s) incl += n;
    }
    int off = running + incl - c;
    running += __shfl(incl, 63);
    const int colbase = ch * 2048;
#pragma unroll
    for (int i = 0; i < 8; ++i) {
      if (v[i].x | v[i].y | v[i].z | v[i].w) {
        const int col = colbase + (i * 64 + lane) * 4;
        if (v[i].x) { if (off < CAP) nbr_row[off] = col + 0; ++off; }
        if (v[i].y) { if (off < CAP) nbr_row[off] = col + 1; ++off; }
        if (v[i].z) { if (off < CAP) nbr_row[off] = col + 2; ++off; }
        if (v[i].w) { if (off < CAP) nbr_row[off] = col + 3; ++off; }
      }
    }
#pragma unroll
    for (int i = 0; i < 8; ++i) v[i] = vn[i];
  }
  if (lane == 0) cnt[row] = running;
}

// ---------------------------------------------------------------------------
// LDS-resident MLP layer for a tile of TILE nodes, 256 threads.
// SCALEMODE: 0 = none, 1 = rowscale[node] (mask), 2 = rsqrt(cnt[node]+1).
// ---------------------------------------------------------------------------
template <int TILE, int K, int KSPLIT, int F, bool RELU, bool BIAS, int SCALEMODE>
__device__ __forceinline__ void layer_op(
    const float (*__restrict__ A0)[AST], const float (*__restrict__ A1)[AST],
    float (*__restrict__ Aout)[AST], float (*__restrict__ Wb)[WST],
    const float* __restrict__ W, const float* __restrict__ bias,
    float* __restrict__ gout, const float* __restrict__ rowscale,
    const int* __restrict__ degcnt, int n0, int t) {
  constexpr int KC = 32;
  constexpr int NCH = K / KC;
  constexpr int ACT = (F * TILE < 256) ? F * TILE : 256;
  constexpr int RS = ACT / F;
  constexpr int RPT = TILE / RS;
  const int c = t % F;
  const int rb = t / F;
  float acc[RPT];
#pragma unroll
  for (int i = 0; i < RPT; ++i) acc[i] = 0.f;

  for (int ch = 0; ch < NCH; ++ch) {
#pragma unroll
    for (int i = 0; i < (F * KC + 255) / 256; ++i) {  // stage W chunk, k-major
      int lin = t + i * 256;
      if ((F * KC) % 256 == 0 || lin < F * KC) {
        int k = lin % KC, f = lin / KC;
        Wb[k][f] = W[(size_t)f * K + ch * KC + k];
      }
    }
    __syncthreads();
    if (t < ACT) {
      const float (*__restrict__ As)[AST] = (ch * KC < KSPLIT) ? A0 : A1;
      const int kb = (ch * KC < KSPLIT) ? ch * KC : ch * KC - KSPLIT;
#pragma unroll
      for (int kg = 0; kg < KC / 4; ++kg) {
        float w0 = Wb[kg * 4 + 0][c];
        float w1v = Wb[kg * 4 + 1][c];
        float w2v = Wb[kg * 4 + 2][c];
        float w3v = Wb[kg * 4 + 3][c];
#pragma unroll
        for (int i = 0; i < RPT; ++i) {
          const float4 a = *(const float4*)&As[rb + i * RS][kb + kg * 4];
          acc[i] = fmaf(a.x, w0, acc[i]);
          acc[i] = fmaf(a.y, w1v, acc[i]);
          acc[i] = fmaf(a.z, w2v, acc[i]);
          acc[i] = fmaf(a.w, w3v, acc[i]);
        }
      }
    }
    __syncthreads();
  }
  if (t < ACT) {
#pragma unroll
    for (int i = 0; i < RPT; ++i) {
      float v = acc[i];
      if (BIAS) v += bias[c];
      if (RELU) v = fmaxf(v, 0.f);
      int node = n0 + rb + i * RS;
      if (SCALEMODE == 1) v *= rowscale[node];
      if (SCALEMODE == 2) v *= rsqrtf((float)degcnt[node] + 1.0f);
      if (Aout) Aout[rb + i * RS][c] = v;
      if (gout) gout[(size_t)node * F + c] = v;
    }
  }
}

// ---------------------------------------------------------------------------
// Kernel 2: encoder x -> h1 -> h ; msg = (h @ wg.T) * dinv  (512 blocks)
// ---------------------------------------------------------------------------
__global__ __launch_bounds__(256) void encode_kernel(
    const float* __restrict__ x,
    const float* __restrict__ w1, const float* __restrict__ b1,
    const float* __restrict__ w2, const float* __restrict__ b2,
    const float* __restrict__ wg, const int* __restrict__ cnt,
    float* __restrict__ h_out, float* __restrict__ msg_out) {
  __shared__ float bufA[ETILE][AST];
  __shared__ float bufB[ETILE][AST];
  __shared__ float Wb[32][WST];
  const int t = threadIdx.x;
  const int n0 = blockIdx.x * ETILE;
  if (t < 128) {  // stage x tile: 16x32 floats = 128 float4
    int row = t >> 3, k4 = (t & 7) * 4;
    *(float4*)&bufA[row][k4] = *(const float4*)&x[(size_t)(n0 + row) * 32 + k4];
  }
  layer_op<ETILE, 32, 32, 64, true, true, 0>(bufA, nullptr, bufB, Wb, w1, b1, nullptr, nullptr, nullptr, n0, t);
  layer_op<ETILE, 64, 64, 128, true, true, 0>(bufB, nullptr, bufA, Wb, w2, b2, h_out, nullptr, nullptr, n0, t);
  layer_op<ETILE, 128, 128, 128, false, false, 2>(bufA, nullptr, nullptr, Wb, wg, nullptr, msg_out, nullptr, cnt, n0, t);
}

// ---------------------------------------------------------------------------
// Kernel 3: agg. 4 rows per 256-thread block; each thread carries TWO row
// accumulators (t>>7 picks the row pair) -> 8 independent gathers in flight.
// Tails predicated; gather index masked to [0,N) so clamped slots never read
// out of bounds (value is predicated off).
// ---------------------------------------------------------------------------
__global__ __launch_bounds__(256) void agg_kernel(
    const int* __restrict__ cnt, const int* __restrict__ nbr,
    const float* __restrict__ msg, const float* __restrict__ bg,
    const float* __restrict__ adj, float* __restrict__ g1) {
  const int t = threadIdx.x;
  const int f = t & 127;
  const int rA = blockIdx.x * 4 + (t >> 7) * 2;
  const int rB = rA + 1;
  const int cA = cnt[rA], cB = cnt[rB];
  float a0 = msg[(size_t)rA * 128 + f];  // self-loop terms (msg pre-scaled)
  float a1 = msg[(size_t)rB * 128 + f];
  if (cA <= CAP && cB <= CAP) {
    const int* nA = nbr + (size_t)rA * CAP;
    const int* nB = nbr + (size_t)rB * CAP;
    const int cm = max(cA, cB);
    for (int i = 0; i < cm; i += 4) {
#pragma unroll
      for (int k = 0; k < 4; ++k) {
        const int ii = i + k;
        int jA = nA[ii < cA ? ii : 0] & (N_NODES - 1);
        int jB = nB[ii < cB ? ii : 0] & (N_NODES - 1);
        float vA = msg[(size_t)jA * 128 + f];
        float vB = msg[(size_t)jB * 128 + f];
        a0 += (ii < cA) ? vA : 0.f;
        a1 += (ii < cB) ? vB : 0.f;
      }
    }
  } else {  // statistically unreachable dense fallback
    a0 = msg[(size_t)rA * 128 + f];
    a1 = msg[(size_t)rB * 128 + f];
    for (int col = 0; col < N_NODES; ++col) {
      if (adj[(size_t)rA * N_NODES + col] != 0.f) a0 += msg[(size_t)col * 128 + f];
      if (adj[(size_t)rB * N_NODES + col] != 0.f) a1 += msg[(size_t)col * 128 + f];
    }
  }
  float o0 = fmaf(rsqrtf((float)cA + 1.0f), a0, bg[f]);
  float o1 = fmaf(rsqrtf((float)cB + 1.0f), a1, bg[f]);
  g1[(size_t)rA * 128 + f] = fmaxf(o0, 0.f);
  g1[(size_t)rB * 128 + f] = fmaxf(o1, 0.f);
}

// ---------------------------------------------------------------------------
// Kernel 4: decoder g1 -> g2 -> p1([g2|h]) -> p2 -> out * mask  (1024 blocks)
// ---------------------------------------------------------------------------
__global__ __launch_bounds__(256) void decode_kernel(
    const float* __restrict__ g1, const float* __restrict__ h,
    const float* __restrict__ wd, const float* __restrict__ bd,
    const float* __restrict__ wp1, const float* __restrict__ bp1,
    const float* __restrict__ wp2, const float* __restrict__ bp2,
    const float* __restrict__ wo, const float* __restrict__ bo,
    const float* __restrict__ mask, float* __restrict__ out) {
  __shared__ float bufA[DTILE][AST];
  __shared__ float bufB[DTILE][AST];
  __shared__ float bufH[DTILE][AST];
  __shared__ float Wb[32][WST];
  const int t = threadIdx.x;
  const int n0 = blockIdx.x * DTILE;
  {  // stage g1 and h tiles (8x128 each = 256 float4 each)
    int row = t >> 5, k4 = (t & 31) * 4;
    *(float4*)&bufA[row][k4] = *(const float4*)&g1[(size_t)(n0 + row) * 128 + k4];
    *(float4*)&bufH[row][k4] = *(const float4*)&h[(size_t)(n0 + row) * 128 + k4];
  }
  layer_op<DTILE, 128, 128, 128, true, true, 0>(bufA, nullptr, bufB, Wb, wd, bd, nullptr, nullptr, nullptr, n0, t);
  layer_op<DTILE, 256, 128, 128, true, true, 0>(bufB, bufH, bufA, Wb, wp1, bp1, nullptr, nullptr, nullptr, n0, t);
  layer_op<DTILE, 128, 128, 64, true, true, 0>(bufA, nullptr, bufB, Wb, wp2, bp2, nullptr, nullptr, nullptr, n0, t);
  layer_op<DTILE, 64, 64, 8, false, true, 1>(bufB, nullptr, nullptr, Wb, wo, bo, out, mask, nullptr, n0, t);
}

extern "C" void kernel_launch(void* const* d_in, const int* in_sizes, int n_in,
                              void* d_out, int out_size, void* d_ws, size_t ws_size,
                              hipStream_t stream) {
  const float* x    = (const float*)d_in[0];
  const float* adj  = (const float*)d_in[1];
  const float* mask = (const float*)d_in[2];
  const float* w1   = (const float*)d_in[3];
  const float* b1   = (const float*)d_in[4];
  const float* w2   = (const float*)d_in[5];
  const float* b2   = (const float*)d_in[6];
  const float* wg   = (const float*)d_in[7];
  const float* bg   = (const float*)d_in[8];
  const float* wd   = (const float*)d_in[9];
  const float* bd   = (const float*)d_in[10];
  const float* wp1  = (const float*)d_in[11];
  const float* bp1  = (const float*)d_in[12];
  const float* wp2  = (const float*)d_in[13];
  const float* bp2  = (const float*)d_in[14];
  const float* wo   = (const float*)d_in[15];
  const float* bo   = (const float*)d_in[16];
  float* out = (float*)d_out;

  float* ws = (float*)d_ws;
  float* h    = ws; ws += (size_t)N_NODES * 128;
  float* msg  = ws; ws += (size_t)N_NODES * 128;
  float* g1   = ws; ws += (size_t)N_NODES * 128;
  int* cnt = (int*)ws; ws += N_NODES;
  int* nbr = (int*)ws;  // N_NODES * CAP ints

  scan_kernel<<<N_NODES / 4, 256, 0, stream>>>(adj, cnt, nbr);
  encode_kernel<<<N_NODES / ETILE, 256, 0, stream>>>(x, w1, b1, w2, b2, wg, cnt, h, msg);
  agg_kernel<<<N_NODES / 4, 256, 0, stream>>>(cnt, nbr, msg, bg, adj, g1);
  decode_kernel<<<N_NODES / DTILE, 256, 0, stream>>>(
      g1, h, wd, bd, wp1, bp1, wp2, bp2, wo, bo, mask, out);
}